// Round 8
// baseline (1161.766 us; speedup 1.0000x reference)
//
#include <hip/hip_runtime.h>

typedef __attribute__((ext_vector_type(8))) short bf16x8;
typedef __attribute__((ext_vector_type(4))) float f32x4;

// ---------------- bf16 split helpers ----------------
__device__ __forceinline__ unsigned f2bf_rne(float f) {
  unsigned u = __float_as_uint(f);
  return (u + 0x7FFFu + ((u >> 16) & 1u)) >> 16;
}
__device__ __forceinline__ float bf2f(unsigned h) { return __uint_as_float(h << 16); }
__device__ __forceinline__ void split_bf(float x, unsigned& hi, unsigned& lo) {
  hi = f2bf_rne(x);
  lo = f2bf_rne(x - bf2f(hi));
}

// ---------------- prep ----------------
__global__ void prep_kernel(const int* __restrict__ num_motifs,
                            const int* __restrict__ batch,
                            int N, int B,
                            int* __restrict__ partial,
                            int* __restrict__ bnd) {
  int t = threadIdx.x;
  if (t == 0) {
    int s = 0;
    for (int b = 0; b < B; ++b) { partial[b] = s; s += num_motifs[b]; }
  }
  if (t <= B) {
    int lo = 0, hi = N;
    while (lo < hi) { int mid = (lo + hi) >> 1; if (batch[mid] < t) lo = mid + 1; else hi = mid; }
    bnd[t] = lo;
  }
}

// ---------------- CSR build ----------------
__global__ __launch_bounds__(256) void hist_kernel(const int* __restrict__ dst, int E,
                                                   int* __restrict__ counts) {
  int e = blockIdx.x * 256 + threadIdx.x;
  if (e < E) atomicAdd(&counts[dst[e]], 1);
}

__global__ __launch_bounds__(1024) void scan_kernel(const int* __restrict__ counts, int n,
                                                    int* __restrict__ base,
                                                    int* __restrict__ cursor) {
  __shared__ int part[1024];
  const int tid = threadIdx.x;
  const int chunk = (n + 1023) / 1024;
  const int lo = tid * chunk;
  const int hi = min(lo + chunk, n);
  int s = 0;
  for (int i = lo; i < hi; ++i) s += counts[i];
  part[tid] = s;
  __syncthreads();
  for (int off = 1; off < 1024; off <<= 1) {
    int v = (tid >= off) ? part[tid - off] : 0;
    __syncthreads();
    part[tid] += v;
    __syncthreads();
  }
  int run = (tid > 0) ? part[tid - 1] : 0;
  for (int i = lo; i < hi; ++i) {
    base[i] = run; cursor[i] = run;
    run += counts[i];
  }
  if (tid == 1023) base[n] = part[1023];
}

// writes packed (eid, src) — one 8B scattered store instead of two 4B
__global__ __launch_bounds__(256) void scatter_kernel(const int* __restrict__ src,
                                                      const int* __restrict__ dst, int E,
                                                      int* __restrict__ cursor,
                                                      int2* __restrict__ ed_s) {
  int e = blockIdx.x * 256 + threadIdx.x;
  if (e >= E) return;
  int d = dst[e];
  int pos = atomicAdd(&cursor[d], 1);
  ed_s[pos] = make_int2(e, src[e]);
}

__global__ __launch_bounds__(256) void nm_hist_kernel(const int* __restrict__ n2m,
                                                      const int* __restrict__ batch,
                                                      const int* __restrict__ partial, int N,
                                                      int* __restrict__ counts) {
  int n = blockIdx.x * 256 + threadIdx.x;
  if (n < N) atomicAdd(&counts[n2m[n] + partial[batch[n]]], 1);
}

__global__ __launch_bounds__(256) void nm_scatter_kernel(const int* __restrict__ n2m,
                                                         const int* __restrict__ batch,
                                                         const int* __restrict__ partial, int N,
                                                         int* __restrict__ cursor,
                                                         int* __restrict__ node_s) {
  int n = blockIdx.x * 256 + threadIdx.x;
  if (n >= N) return;
  int m = n2m[n] + partial[batch[n]];
  node_s[atomicAdd(&cursor[m], 1)] = n;
}

// ---- GINE layer 0: gathers ea[eid], ALSO writes ea into CSR order (ea_s, sequential) ----
__global__ __launch_bounds__(128) void gine_first_kernel(
    const float* __restrict__ x, const float* __restrict__ ea,
    const int* __restrict__ base, const int2* __restrict__ ed_s,
    float* __restrict__ ea_s, float* __restrict__ h, int N) {
  const int n = blockIdx.x * 2 + (threadIdx.x >> 6);
  if (n >= N) return;
  const int d2 = (threadIdx.x & 63) * 2;
  const int e0 = base[n], e1 = base[n + 1];
  float sx = 0.f, sy = 0.f;
  int j = e0;
  for (; j + 1 < e1; j += 2) {
    int2 eA = ed_s[j], eB = ed_s[j + 1];
    float2 ja = *(const float2*)&ea[(long long)eA.x * 128 + d2];
    float2 jb = *(const float2*)&ea[(long long)eB.x * 128 + d2];
    float2 xa = *(const float2*)&x[eA.y * 128 + d2];
    float2 xb = *(const float2*)&x[eB.y * 128 + d2];
    *(float2*)&ea_s[(long long)j * 128 + d2] = ja;
    *(float2*)&ea_s[(long long)(j + 1) * 128 + d2] = jb;
    sx += fmaxf(xa.x + ja.x, 0.f) + fmaxf(xb.x + jb.x, 0.f);
    sy += fmaxf(xa.y + ja.y, 0.f) + fmaxf(xb.y + jb.y, 0.f);
  }
  if (j < e1) {
    int2 eA = ed_s[j];
    float2 ja = *(const float2*)&ea[(long long)eA.x * 128 + d2];
    float2 xa = *(const float2*)&x[eA.y * 128 + d2];
    *(float2*)&ea_s[(long long)j * 128 + d2] = ja;
    sx += fmaxf(xa.x + ja.x, 0.f);
    sy += fmaxf(xa.y + ja.y, 0.f);
  }
  float2 xv = *(const float2*)&x[n * 128 + d2];
  *(float2*)&h[n * 128 + d2] = make_float2(xv.x + sx, xv.y + sy);
}

// ---- GINE layers 1,2: ea_s read is fully sequential (streaming) ----
__global__ __launch_bounds__(128) void gine_rest_kernel(
    const float* __restrict__ x, const float* __restrict__ ea_s,
    const int* __restrict__ base, const int2* __restrict__ ed_s,
    float* __restrict__ h, int N) {
  const int n = blockIdx.x * 2 + (threadIdx.x >> 6);
  if (n >= N) return;
  const int d2 = (threadIdx.x & 63) * 2;
  const int e0 = base[n], e1 = base[n + 1];
  float sx = 0.f, sy = 0.f;
  int j = e0;
  for (; j + 3 < e1; j += 4) {
    int s0 = ed_s[j].y, s1 = ed_s[j + 1].y, s2 = ed_s[j + 2].y, s3 = ed_s[j + 3].y;
    float2 j0 = *(const float2*)&ea_s[(long long)j * 128 + d2];
    float2 j1 = *(const float2*)&ea_s[(long long)(j + 1) * 128 + d2];
    float2 j2 = *(const float2*)&ea_s[(long long)(j + 2) * 128 + d2];
    float2 j3 = *(const float2*)&ea_s[(long long)(j + 3) * 128 + d2];
    float2 x0 = *(const float2*)&x[s0 * 128 + d2];
    float2 x1 = *(const float2*)&x[s1 * 128 + d2];
    float2 x2 = *(const float2*)&x[s2 * 128 + d2];
    float2 x3 = *(const float2*)&x[s3 * 128 + d2];
    sx += fmaxf(x0.x + j0.x, 0.f) + fmaxf(x1.x + j1.x, 0.f)
        + fmaxf(x2.x + j2.x, 0.f) + fmaxf(x3.x + j3.x, 0.f);
    sy += fmaxf(x0.y + j0.y, 0.f) + fmaxf(x1.y + j1.y, 0.f)
        + fmaxf(x2.y + j2.y, 0.f) + fmaxf(x3.y + j3.y, 0.f);
  }
  for (; j < e1; ++j) {
    int s0 = ed_s[j].y;
    float2 j0 = *(const float2*)&ea_s[(long long)j * 128 + d2];
    float2 x0 = *(const float2*)&x[s0 * 128 + d2];
    sx += fmaxf(x0.x + j0.x, 0.f);
    sy += fmaxf(x0.y + j0.y, 0.f);
  }
  float2 xv = *(const float2*)&x[n * 128 + d2];
  *(float2*)&h[n * 128 + d2] = make_float2(xv.x + sx, xv.y + sy);
}

// ---- GIN pull-aggregate fused with self ----
__global__ __launch_bounds__(128) void gin_agg_kernel(
    const float* __restrict__ hi, const int* __restrict__ base,
    const int2* __restrict__ ed_s, float* __restrict__ ho, int M) {
  const int m = blockIdx.x * 2 + (threadIdx.x >> 6);
  if (m >= M) return;
  const int d2 = (threadIdx.x & 63) * 2;
  const int e0 = base[m], e1 = base[m + 1];
  float sx = 0.f, sy = 0.f;
  int j = e0;
  for (; j + 1 < e1; j += 2) {
    float2 a = *(const float2*)&hi[ed_s[j].y * 128 + d2];
    float2 b = *(const float2*)&hi[ed_s[j + 1].y * 128 + d2];
    sx += a.x + b.x; sy += a.y + b.y;
  }
  if (j < e1) {
    float2 a = *(const float2*)&hi[ed_s[j].y * 128 + d2];
    sx += a.x; sy += a.y;
  }
  float2 hv = *(const float2*)&hi[m * 128 + d2];
  *(float2*)&ho[m * 128 + d2] = make_float2(hv.x + sx, hv.y + sy);
}

// ---- motif gather: xm_h[m,d] = emb[motifid[m],d] + sum_{nodes in m} xm_nodes[node,d] ----
__global__ __launch_bounds__(128) void motif_gather_kernel(
    const float* __restrict__ xm_nodes, const int* __restrict__ mb,
    const int* __restrict__ node_s, const int* __restrict__ motifid,
    const float* __restrict__ emb, float* __restrict__ xm_h, int M) {
  const int m = blockIdx.x * 2 + (threadIdx.x >> 6);
  if (m >= M) return;
  const int d2 = (threadIdx.x & 63) * 2;
  float2 e = *(const float2*)&emb[motifid[m] * 128 + d2];
  float sx = e.x, sy = e.y;
  const int j0 = mb[m], j1 = mb[m + 1];
  int j = j0;
  for (; j + 1 < j1; j += 2) {
    float2 a = *(const float2*)&xm_nodes[(long long)node_s[j] * 128 + d2];
    float2 b = *(const float2*)&xm_nodes[(long long)node_s[j + 1] * 128 + d2];
    sx += a.x + b.x; sy += a.y + b.y;
  }
  if (j < j1) {
    float2 a = *(const float2*)&xm_nodes[(long long)node_s[j] * 128 + d2];
    sx += a.x; sy += a.y;
  }
  *(float2*)&xm_h[m * 128 + d2] = make_float2(sx, sy);
}

// ---------------- weight preconversion: fp32 [128][128] -> fragment-ordered bf16 hi/lo ----------------
struct WSrc { const float* p[13]; };

__global__ __launch_bounds__(256) void convw_kernel(WSrc wsrc, ushort* __restrict__ Wf) {
  const int mat = blockIdx.x >> 2;
  const int kc  = blockIdx.x & 3;
  const float* W = wsrc.p[mat];
  const int t = threadIdx.x;
  #pragma unroll
  for (int i = 0; i < 16; ++i) {
    int o = t * 16 + i;
    int nt = o >> 9, lane = (o >> 3) & 63, j = o & 7;
    int k = kc * 32 + (lane >> 4) * 8 + j;
    int n = nt * 16 + (lane & 15);
    unsigned hi, lo;
    split_bf(W[k * 128 + n], hi, lo);
    Wf[mat * 32768 + kc * 4096 + o]         = (ushort)hi;
    Wf[mat * 32768 + 16384 + kc * 4096 + o] = (ushort)lo;
  }
}

// ---------------- MFMA GEMM core (128x128 tile, 4 waves, 64x64 per wave) ----------------
__device__ __forceinline__ void stage_a_bf(ushort* AsH, ushort* AsL,
                                           const float* __restrict__ src,
                                           int row0, int nrows, int tid) {
  #pragma unroll
  for (int it = 0; it < 16; ++it) {
    int idx = (it * 256 + tid) * 4;
    int r = idx >> 7, k = idx & 127;
    float4 v = make_float4(0.f, 0.f, 0.f, 0.f);
    if (row0 + r < nrows) v = *(const float4*)&src[(long long)(row0 + r) * 128 + k];
    unsigned h0, l0, h1, l1, h2, l2, h3, l3;
    split_bf(v.x, h0, l0); split_bf(v.y, h1, l1);
    split_bf(v.z, h2, l2); split_bf(v.w, h3, l3);
    uint2 ph = make_uint2(h0 | (h1 << 16), h2 | (h3 << 16));
    uint2 pl = make_uint2(l0 | (l1 << 16), l2 | (l3 << 16));
    int boff = r * 256 + ((k * 2) ^ ((r & 7) << 4));
    *(uint2*)((char*)AsH + boff) = ph;
    *(uint2*)((char*)AsL + boff) = pl;
  }
}

__device__ __forceinline__ bf16x8 ld_afrag(const ushort* As, int row, int k0) {
  int boff = row * 256 + ((k0 * 2) ^ ((row & 7) << 4));
  return *(const bf16x8*)((const char*)As + boff);
}

__device__ __forceinline__ bf16x8 ld_wfrag(const ushort* Wf, int kc, int nt, int lane) {
  return ((const bf16x8*)Wf)[(kc * 8 + nt) * 64 + lane];
}

__device__ __forceinline__ void mfma_gemm(const ushort* AsH, const ushort* AsL,
                                          const ushort* WfH, const ushort* WfL,
                                          int wr, int wc, int lane, f32x4 (&acc)[4][4]) {
  #pragma unroll
  for (int kc = 0; kc < 4; ++kc) {
    const int k0 = kc * 32 + (lane >> 4) * 8;
    bf16x8 ah[4], al[4], wh[4], wl[4];
    #pragma unroll
    for (int rt = 0; rt < 4; ++rt) {
      int row = wr * 64 + rt * 16 + (lane & 15);
      ah[rt] = ld_afrag(AsH, row, k0);
      al[rt] = ld_afrag(AsL, row, k0);
    }
    #pragma unroll
    for (int ct = 0; ct < 4; ++ct) {
      int nt = wc * 4 + ct;
      wh[ct] = ld_wfrag(WfH, kc, nt, lane);
      wl[ct] = ld_wfrag(WfL, kc, nt, lane);
    }
    #pragma unroll
    for (int rt = 0; rt < 4; ++rt)
      #pragma unroll
      for (int ct = 0; ct < 4; ++ct) {
        acc[rt][ct] = __builtin_amdgcn_mfma_f32_16x16x32_bf16(ah[rt], wh[ct], acc[rt][ct], 0, 0, 0);
        acc[rt][ct] = __builtin_amdgcn_mfma_f32_16x16x32_bf16(ah[rt], wl[ct], acc[rt][ct], 0, 0, 0);
        acc[rt][ct] = __builtin_amdgcn_mfma_f32_16x16x32_bf16(al[rt], wh[ct], acc[rt][ct], 0, 0, 0);
      }
  }
}

__device__ __forceinline__ void bias_acc(f32x4 (&acc)[4][4], const float* __restrict__ b,
                                         int wc, int lane) {
  #pragma unroll
  for (int ct = 0; ct < 4; ++ct) {
    float bv = b[wc * 64 + ct * 16 + (lane & 15)];
    #pragma unroll
    for (int rt = 0; rt < 4; ++rt) acc[rt][ct] = (f32x4){bv, bv, bv, bv};
  }
}

// out = relu( relu(h@W1 + b1) @ W2 + b2 ), fused two GEMMs
__global__ __launch_bounds__(256, 2) void mlp_mfma_kernel(
    const float* __restrict__ h,
    const ushort* __restrict__ W1f, const float* __restrict__ b1,
    const ushort* __restrict__ W2f, const float* __restrict__ b2,
    float* __restrict__ out, int nrows) {
  __shared__ ushort AsH[128 * 128];
  __shared__ ushort AsL[128 * 128];
  const int tid = threadIdx.x;
  const int lane = tid & 63;
  const int w = tid >> 6;
  const int wr = w >> 1, wc = w & 1;
  const int row0 = blockIdx.x * 128;

  stage_a_bf(AsH, AsL, h, row0, nrows, tid);
  __syncthreads();

  f32x4 acc[4][4];
  bias_acc(acc, b1, wc, lane);
  mfma_gemm(AsH, AsL, W1f, W1f + 16384, wr, wc, lane, acc);
  __syncthreads();

  #pragma unroll
  for (int rt = 0; rt < 4; ++rt)
    #pragma unroll
    for (int ct = 0; ct < 4; ++ct) {
      int col = wc * 64 + ct * 16 + (lane & 15);
      #pragma unroll
      for (int r = 0; r < 4; ++r) {
        int row = wr * 64 + rt * 16 + (lane >> 4) * 4 + r;
        unsigned hi, lo;
        split_bf(fmaxf(acc[rt][ct][r], 0.f), hi, lo);
        int boff = row * 256 + ((col * 2) ^ ((row & 7) << 4));
        *(ushort*)((char*)AsH + boff) = (ushort)hi;
        *(ushort*)((char*)AsL + boff) = (ushort)lo;
      }
    }
  __syncthreads();

  f32x4 acc2[4][4];
  bias_acc(acc2, b2, wc, lane);
  mfma_gemm(AsH, AsL, W2f, W2f + 16384, wr, wc, lane, acc2);

  #pragma unroll
  for (int rt = 0; rt < 4; ++rt)
    #pragma unroll
    for (int ct = 0; ct < 4; ++ct) {
      int col = wc * 64 + ct * 16 + (lane & 15);
      #pragma unroll
      for (int r = 0; r < 4; ++r) {
        int row = row0 + wr * 64 + rt * 16 + (lane >> 4) * 4 + r;
        if (row < nrows) out[(long long)row * 128 + col] = fmaxf(acc2[rt][ct][r], 0.f);
      }
    }
}

// xm_nodes = relu([x1|x2|x3] @ lin_W + lin_b), K=384 via 3 staged chunks
__global__ __launch_bounds__(256, 2) void lin_mfma_kernel(
    const float* __restrict__ x1, const float* __restrict__ x2, const float* __restrict__ x3,
    const ushort* __restrict__ Wlf, const float* __restrict__ lb,
    float* __restrict__ xm_nodes, int nrows) {
  __shared__ ushort AsH[128 * 128];
  __shared__ ushort AsL[128 * 128];
  const int tid = threadIdx.x;
  const int lane = tid & 63;
  const int w = tid >> 6;
  const int wr = w >> 1, wc = w & 1;
  const int row0 = blockIdx.x * 128;

  f32x4 acc[4][4];
  bias_acc(acc, lb, wc, lane);

  for (int c3 = 0; c3 < 3; ++c3) {
    const float* xs = (c3 == 0) ? x1 : (c3 == 1 ? x2 : x3);
    if (c3) __syncthreads();
    stage_a_bf(AsH, AsL, xs, row0, nrows, tid);
    __syncthreads();
    const ushort* Wc = Wlf + c3 * 32768;
    mfma_gemm(AsH, AsL, Wc, Wc + 16384, wr, wc, lane, acc);
  }

  #pragma unroll
  for (int rt = 0; rt < 4; ++rt)
    #pragma unroll
    for (int ct = 0; ct < 4; ++ct) {
      int col = wc * 64 + ct * 16 + (lane & 15);
      #pragma unroll
      for (int r = 0; r < 4; ++r) {
        int row = row0 + wr * 64 + rt * 16 + (lane >> 4) * 4 + r;
        if (row < nrows) xm_nodes[(long long)row * 128 + col] = fmaxf(acc[rt][ct][r], 0.f);
      }
    }
}

// chunked node pooling over sorted batch[]
__global__ __launch_bounds__(192) void xg_pool_kernel(
    const float* __restrict__ x1, const float* __restrict__ x2, const float* __restrict__ x3,
    const int* __restrict__ batch, int N, int chunk, float* __restrict__ outg) {
  const int c0 = blockIdx.x * chunk;
  if (c0 >= N) return;
  const int c1 = min(c0 + chunk, N);
  const int l = threadIdx.x >> 6;
  const int d2 = (threadIdx.x & 63) * 2;
  const float* xs = (l == 0) ? x1 : (l == 1 ? x2 : x3);
  int b = batch[c0];
  float sx = 0.f, sy = 0.f;
  for (int n = c0; n < c1; ++n) {
    int bn = batch[n];
    if (bn != b) {
      if (sx != 0.f) atomicAdd(&outg[b * 384 + l * 128 + d2], sx);
      if (sy != 0.f) atomicAdd(&outg[b * 384 + l * 128 + d2 + 1], sy);
      sx = 0.f; sy = 0.f; b = bn;
    }
    float2 v = *(const float2*)&xs[n * 128 + d2];
    sx += v.x; sy += v.y;
  }
  atomicAdd(&outg[b * 384 + l * 128 + d2], sx);
  atomicAdd(&outg[b * 384 + l * 128 + d2 + 1], sy);
}

// chunked motif pooling
__global__ __launch_bounds__(128) void xm_pool_kernel(
    const float* __restrict__ m1, const float* __restrict__ m2,
    const int* __restrict__ partial, int B, int M, int chunk,
    float* __restrict__ outm) {
  const int c0 = blockIdx.x * chunk;
  if (c0 >= M) return;
  const int c1 = min(c0 + chunk, M);
  const int l = threadIdx.x >> 6;
  const int d2 = (threadIdx.x & 63) * 2;
  const float* ms = (l == 0) ? m1 : m2;
  int b = 0;
  while (b + 1 < B && partial[b + 1] <= c0) ++b;
  int bend = (b + 1 < B) ? partial[b + 1] : M;
  float sx = 0.f, sy = 0.f;
  for (int m = c0; m < c1; ++m) {
    if (m >= bend) {
      if (sx != 0.f) atomicAdd(&outm[b * 256 + l * 128 + d2], sx);
      if (sy != 0.f) atomicAdd(&outm[b * 256 + l * 128 + d2 + 1], sy);
      sx = 0.f; sy = 0.f;
      do { ++b; } while (b + 1 < B && partial[b + 1] <= m);
      bend = (b + 1 < B) ? partial[b + 1] : M;
    }
    float2 v = *(const float2*)&ms[m * 128 + d2];
    sx += v.x; sy += v.y;
  }
  atomicAdd(&outm[b * 256 + l * 128 + d2], sx);
  atomicAdd(&outm[b * 256 + l * 128 + d2 + 1], sy);
}

extern "C" void kernel_launch(void* const* d_in, const int* in_sizes, int n_in,
                              void* d_out, int out_size, void* d_ws, size_t ws_size,
                              hipStream_t stream) {
  const float* x       = (const float*)d_in[0];
  const float* ea      = (const float*)d_in[1];
  const int*   eidx    = (const int*)d_in[2];
  const int*   batch   = (const int*)d_in[3];
  const int*   n2m     = (const int*)d_in[4];
  const int*   nmot    = (const int*)d_in[5];
  const int*   meidx   = (const int*)d_in[6];
  const int*   motifid = (const int*)d_in[7];
  const float* gcW1 = (const float*)d_in[8];
  const float* gcb1 = (const float*)d_in[9];
  const float* gcW2 = (const float*)d_in[10];
  const float* gcb2 = (const float*)d_in[11];
  const float* mcW1 = (const float*)d_in[12];
  const float* mcb1 = (const float*)d_in[13];
  const float* mcW2 = (const float*)d_in[14];
  const float* mcb2 = (const float*)d_in[15];
  const float* linW = (const float*)d_in[16];
  const float* linb = (const float*)d_in[17];
  const float* emb  = (const float*)d_in[18];
  float* outp = (float*)d_out;

  const int N  = in_sizes[0] / 128;   // 50000
  const int E  = in_sizes[1] / 128;   // 600000
  const int B  = in_sizes[5];         // 64
  const int ME = in_sizes[6] / 2;     // 50000
  const int M  = in_sizes[7];         // 6400

  const size_t nodeBytes = (size_t)N * 128 * 4;
  const size_t motBytes  = (size_t)M * 128 * 4;
  char* ws = (char*)d_ws;
  float* xl0 = (float*)ws;                 ws += nodeBytes;
  float* xl1 = (float*)ws;                 ws += nodeBytes;
  float* xl2 = (float*)ws;                 ws += nodeBytes;
  char*  R   = ws;                         ws += nodeBytes;   // h during GINE; xm_nodes after
  float* ea_s = (float*)ws;                ws += (size_t)E * 128 * 4;   // 307 MB CSR-ordered ea
  ushort* Wf = (ushort*)ws;                ws += (size_t)13 * 32768 * 2;
  int* counts  = (int*)ws;                 ws += (size_t)N * 4;
  int* base    = (int*)ws;                 ws += (size_t)(N + 1) * 4;
  int* cursor  = (int*)ws;                 ws += (size_t)N * 4;
  int2* ed_s   = (int2*)ws;                ws += (size_t)E * 8;
  int* mcounts = (int*)ws;                 ws += (size_t)M * 4;
  int* mbase   = (int*)ws;                 ws += (size_t)(M + 1) * 4;
  int* mcursor = (int*)ws;                 ws += (size_t)M * 4;
  int2* med_s  = (int2*)ws;                ws += (size_t)ME * 8;
  int* nmcnt   = (int*)ws;                 ws += (size_t)M * 4;
  int* nmbase  = (int*)ws;                 ws += (size_t)(M + 1) * 4;
  int* nmcur   = (int*)ws;                 ws += (size_t)M * 4;
  int* node_s  = (int*)ws;                 ws += (size_t)N * 4;
  int* partial = (int*)ws;                 ws += 256;
  int* bnd     = (int*)ws;                 ws += 512;
  if ((size_t)(ws - (char*)d_ws) > ws_size) return;

  float* hbuf     = (float*)R;
  float* xm_nodes = (float*)R;
  float* xmh = (float*)((char*)xl0);
  float* hm  = (float*)((char*)xl0 + motBytes);
  float* ml0 = (float*)((char*)xl0 + 2 * motBytes);
  float* ml1 = (float*)((char*)xl0 + 3 * motBytes);

  hipMemsetAsync(outp, 0, (size_t)out_size * 4, stream);

  prep_kernel<<<1, 128, 0, stream>>>(nmot, batch, N, B, partial, bnd);

  // ---- preconvert weights ----
  WSrc wsrc;
  wsrc.p[0] = gcW1;            wsrc.p[1] = gcW1 + 16384;  wsrc.p[2] = gcW1 + 32768;
  wsrc.p[3] = gcW2;            wsrc.p[4] = gcW2 + 16384;  wsrc.p[5] = gcW2 + 32768;
  wsrc.p[6] = mcW1;            wsrc.p[7] = mcW1 + 16384;
  wsrc.p[8] = mcW2;            wsrc.p[9] = mcW2 + 16384;
  wsrc.p[10] = linW;           wsrc.p[11] = linW + 16384; wsrc.p[12] = linW + 32768;
  convw_kernel<<<52, 256, 0, stream>>>(wsrc, Wf);

  // ---- node-graph CSR by dst (packed eid,src) ----
  const int* src = eidx;
  const int* dst = eidx + E;
  hipMemsetAsync(counts, 0, (size_t)N * 4, stream);
  hist_kernel<<<(E + 255) / 256, 256, 0, stream>>>(dst, E, counts);
  scan_kernel<<<1, 1024, 0, stream>>>(counts, N, base, cursor);
  scatter_kernel<<<(E + 255) / 256, 256, 0, stream>>>(src, dst, E, cursor, ed_s);

  // ---- motif-graph CSR by dst ----
  const int* msrc = meidx;
  const int* mdst = meidx + ME;
  hipMemsetAsync(mcounts, 0, (size_t)M * 4, stream);
  hist_kernel<<<(ME + 255) / 256, 256, 0, stream>>>(mdst, ME, mcounts);
  scan_kernel<<<1, 1024, 0, stream>>>(mcounts, M, mbase, mcursor);
  scatter_kernel<<<(ME + 255) / 256, 256, 0, stream>>>(msrc, mdst, ME, mcursor, med_s);

  // ---- node->motif CSR ----
  hipMemsetAsync(nmcnt, 0, (size_t)M * 4, stream);
  nm_hist_kernel<<<(N + 255) / 256, 256, 0, stream>>>(n2m, batch, partial, N, nmcnt);
  scan_kernel<<<1, 1024, 0, stream>>>(nmcnt, M, nmbase, nmcur);
  nm_scatter_kernel<<<(N + 255) / 256, 256, 0, stream>>>(n2m, batch, partial, N, nmcur, node_s);

  // ---- GINE stack ----
  float* xo[3] = {xl0, xl1, xl2};
  const int ngrid = (N + 127) / 128;
  // layer 0: gather ea + emit CSR-ordered copy
  gine_first_kernel<<<(N + 1) / 2, 128, 0, stream>>>(x, ea, base, ed_s, ea_s, hbuf, N);
  mlp_mfma_kernel<<<ngrid, 256, 0, stream>>>(hbuf,
      Wf + (size_t)0 * 32768, gcb1, Wf + (size_t)3 * 32768, gcb2, xl0, N);
  // layers 1,2: stream ea_s sequentially
  for (int i = 1; i < 3; ++i) {
    gine_rest_kernel<<<(N + 1) / 2, 128, 0, stream>>>(xo[i - 1], ea_s, base, ed_s, hbuf, N);
    mlp_mfma_kernel<<<ngrid, 256, 0, stream>>>(hbuf,
        Wf + (size_t)(0 + i) * 32768, gcb1 + i * 128,
        Wf + (size_t)(3 + i) * 32768, gcb2 + i * 128, xo[i], N);
  }
  {
    const int nb = 512;
    const int chunk = (N + nb - 1) / nb;
    xg_pool_kernel<<<nb, 192, 0, stream>>>(xl0, xl1, xl2, batch, N, chunk, outp + B * 256);
  }

  // ---- motif features ----
  lin_mfma_kernel<<<ngrid, 256, 0, stream>>>(xl0, xl1, xl2, Wf + (size_t)10 * 32768, linb,
                                             xm_nodes, N);
  motif_gather_kernel<<<(M + 1) / 2, 128, 0, stream>>>(xm_nodes, nmbase, node_s,
                                                       motifid, emb, xmh, M);

  // ---- motif GIN stack ----
  const float* hs[2] = {xmh, ml0};
  float* mo[2] = {ml0, ml1};
  const int mgrid = (M + 127) / 128;
  for (int i = 0; i < 2; ++i) {
    gin_agg_kernel<<<(M + 1) / 2, 128, 0, stream>>>(hs[i], mbase, med_s, hm, M);
    mlp_mfma_kernel<<<mgrid, 256, 0, stream>>>(hm,
        Wf + (size_t)(6 + i) * 32768, mcb1 + i * 128,
        Wf + (size_t)(8 + i) * 32768, mcb2 + i * 128, mo[i], M);
  }
  {
    const int nb = 256;
    const int chunk = (M + nb - 1) / nb;
    xm_pool_kernel<<<nb, 128, 0, stream>>>(ml0, ml1, partial, B, M, chunk, outp);
  }
}

// Round 9
// 1047.530 us; speedup vs baseline: 1.1091x; 1.1091x over previous
//
#include <hip/hip_runtime.h>
#include <hip/hip_fp16.h>

typedef __attribute__((ext_vector_type(8))) short bf16x8;
typedef __attribute__((ext_vector_type(4))) float f32x4;

// ---------------- bf16 split helpers ----------------
__device__ __forceinline__ unsigned f2bf_rne(float f) {
  unsigned u = __float_as_uint(f);
  return (u + 0x7FFFu + ((u >> 16) & 1u)) >> 16;
}
__device__ __forceinline__ float bf2f(unsigned h) { return __uint_as_float(h << 16); }
__device__ __forceinline__ void split_bf(float x, unsigned& hi, unsigned& lo) {
  hi = f2bf_rne(x);
  lo = f2bf_rne(x - bf2f(hi));
}

// ---------------- prep ----------------
__global__ void prep_kernel(const int* __restrict__ num_motifs,
                            const int* __restrict__ batch,
                            int N, int B,
                            int* __restrict__ partial,
                            int* __restrict__ bnd) {
  int t = threadIdx.x;
  if (t == 0) {
    int s = 0;
    for (int b = 0; b < B; ++b) { partial[b] = s; s += num_motifs[b]; }
  }
  if (t <= B) {
    int lo = 0, hi = N;
    while (lo < hi) { int mid = (lo + hi) >> 1; if (batch[mid] < t) lo = mid + 1; else hi = mid; }
    bnd[t] = lo;
  }
}

// ---------------- CSR build ----------------
__global__ __launch_bounds__(256) void hist_kernel(const int* __restrict__ dst, int E,
                                                   int* __restrict__ counts) {
  int e = blockIdx.x * 256 + threadIdx.x;
  if (e < E) atomicAdd(&counts[dst[e]], 1);
}

__global__ __launch_bounds__(1024) void scan_kernel(const int* __restrict__ counts, int n,
                                                    int* __restrict__ base,
                                                    int* __restrict__ cursor) {
  __shared__ int part[1024];
  const int tid = threadIdx.x;
  const int chunk = (n + 1023) / 1024;
  const int lo = tid * chunk;
  const int hi = min(lo + chunk, n);
  int s = 0;
  for (int i = lo; i < hi; ++i) s += counts[i];
  part[tid] = s;
  __syncthreads();
  for (int off = 1; off < 1024; off <<= 1) {
    int v = (tid >= off) ? part[tid - off] : 0;
    __syncthreads();
    part[tid] += v;
    __syncthreads();
  }
  int run = (tid > 0) ? part[tid - 1] : 0;
  for (int i = lo; i < hi; ++i) {
    base[i] = run; cursor[i] = run;
    run += counts[i];
  }
  if (tid == 1023) base[n] = part[1023];
}

__global__ __launch_bounds__(256) void scatter_kernel(const int* __restrict__ src,
                                                      const int* __restrict__ dst, int E,
                                                      int* __restrict__ cursor,
                                                      int2* __restrict__ ed_s) {
  int e = blockIdx.x * 256 + threadIdx.x;
  if (e >= E) return;
  int d = dst[e];
  int pos = atomicAdd(&cursor[d], 1);
  ed_s[pos] = make_int2(e, src[e]);
}

__global__ __launch_bounds__(256) void nm_hist_kernel(const int* __restrict__ n2m,
                                                      const int* __restrict__ batch,
                                                      const int* __restrict__ partial, int N,
                                                      int* __restrict__ counts) {
  int n = blockIdx.x * 256 + threadIdx.x;
  if (n < N) atomicAdd(&counts[n2m[n] + partial[batch[n]]], 1);
}

__global__ __launch_bounds__(256) void nm_scatter_kernel(const int* __restrict__ n2m,
                                                         const int* __restrict__ batch,
                                                         const int* __restrict__ partial, int N,
                                                         int* __restrict__ cursor,
                                                         int* __restrict__ node_s) {
  int n = blockIdx.x * 256 + threadIdx.x;
  if (n >= N) return;
  int m = n2m[n] + partial[batch[n]];
  node_s[atomicAdd(&cursor[m], 1)] = n;
}

// ---- GINE layer 0: gathers ea[eid] (fp32), writes fp16 CSR-ordered copy ea_s ----
__global__ __launch_bounds__(128) void gine_first_kernel(
    const float* __restrict__ x, const float* __restrict__ ea,
    const int* __restrict__ base, const int2* __restrict__ ed_s,
    __half* __restrict__ ea_s, float* __restrict__ h, int N) {
  const int n = blockIdx.x * 2 + (threadIdx.x >> 6);
  if (n >= N) return;
  const int d2 = (threadIdx.x & 63) * 2;
  const int e0 = base[n], e1 = base[n + 1];
  float sx = 0.f, sy = 0.f;
  int j = e0;
  for (; j + 1 < e1; j += 2) {
    int2 eA = ed_s[j], eB = ed_s[j + 1];
    float2 ja = *(const float2*)&ea[(long long)eA.x * 128 + d2];
    float2 jb = *(const float2*)&ea[(long long)eB.x * 128 + d2];
    float2 xa = *(const float2*)&x[eA.y * 128 + d2];
    float2 xb = *(const float2*)&x[eB.y * 128 + d2];
    *(__half2*)&ea_s[(long long)j * 128 + d2] = __float22half2_rn(ja);
    *(__half2*)&ea_s[(long long)(j + 1) * 128 + d2] = __float22half2_rn(jb);
    sx += fmaxf(xa.x + ja.x, 0.f) + fmaxf(xb.x + jb.x, 0.f);
    sy += fmaxf(xa.y + ja.y, 0.f) + fmaxf(xb.y + jb.y, 0.f);
  }
  if (j < e1) {
    int2 eA = ed_s[j];
    float2 ja = *(const float2*)&ea[(long long)eA.x * 128 + d2];
    float2 xa = *(const float2*)&x[eA.y * 128 + d2];
    *(__half2*)&ea_s[(long long)j * 128 + d2] = __float22half2_rn(ja);
    sx += fmaxf(xa.x + ja.x, 0.f);
    sy += fmaxf(xa.y + ja.y, 0.f);
  }
  float2 xv = *(const float2*)&x[n * 128 + d2];
  *(float2*)&h[n * 128 + d2] = make_float2(xv.x + sx, xv.y + sy);
}

// ---- GINE layers 1,2: ea_s (fp16) read fully sequentially ----
__global__ __launch_bounds__(128) void gine_rest_kernel(
    const float* __restrict__ x, const __half* __restrict__ ea_s,
    const int* __restrict__ base, const int2* __restrict__ ed_s,
    float* __restrict__ h, int N) {
  const int n = blockIdx.x * 2 + (threadIdx.x >> 6);
  if (n >= N) return;
  const int d2 = (threadIdx.x & 63) * 2;
  const int e0 = base[n], e1 = base[n + 1];
  float sx = 0.f, sy = 0.f;
  int j = e0;
  for (; j + 3 < e1; j += 4) {
    int s0 = ed_s[j].y, s1 = ed_s[j + 1].y, s2 = ed_s[j + 2].y, s3 = ed_s[j + 3].y;
    float2 j0 = __half22float2(*(const __half2*)&ea_s[(long long)j * 128 + d2]);
    float2 j1 = __half22float2(*(const __half2*)&ea_s[(long long)(j + 1) * 128 + d2]);
    float2 j2 = __half22float2(*(const __half2*)&ea_s[(long long)(j + 2) * 128 + d2]);
    float2 j3 = __half22float2(*(const __half2*)&ea_s[(long long)(j + 3) * 128 + d2]);
    float2 x0 = *(const float2*)&x[s0 * 128 + d2];
    float2 x1 = *(const float2*)&x[s1 * 128 + d2];
    float2 x2 = *(const float2*)&x[s2 * 128 + d2];
    float2 x3 = *(const float2*)&x[s3 * 128 + d2];
    sx += fmaxf(x0.x + j0.x, 0.f) + fmaxf(x1.x + j1.x, 0.f)
        + fmaxf(x2.x + j2.x, 0.f) + fmaxf(x3.x + j3.x, 0.f);
    sy += fmaxf(x0.y + j0.y, 0.f) + fmaxf(x1.y + j1.y, 0.f)
        + fmaxf(x2.y + j2.y, 0.f) + fmaxf(x3.y + j3.y, 0.f);
  }
  for (; j < e1; ++j) {
    int s0 = ed_s[j].y;
    float2 j0 = __half22float2(*(const __half2*)&ea_s[(long long)j * 128 + d2]);
    float2 x0 = *(const float2*)&x[s0 * 128 + d2];
    sx += fmaxf(x0.x + j0.x, 0.f);
    sy += fmaxf(x0.y + j0.y, 0.f);
  }
  float2 xv = *(const float2*)&x[n * 128 + d2];
  *(float2*)&h[n * 128 + d2] = make_float2(xv.x + sx, xv.y + sy);
}

// ---- GIN pull-aggregate fused with self ----
__global__ __launch_bounds__(128) void gin_agg_kernel(
    const float* __restrict__ hi, const int* __restrict__ base,
    const int2* __restrict__ ed_s, float* __restrict__ ho, int M) {
  const int m = blockIdx.x * 2 + (threadIdx.x >> 6);
  if (m >= M) return;
  const int d2 = (threadIdx.x & 63) * 2;
  const int e0 = base[m], e1 = base[m + 1];
  float sx = 0.f, sy = 0.f;
  int j = e0;
  for (; j + 1 < e1; j += 2) {
    float2 a = *(const float2*)&hi[ed_s[j].y * 128 + d2];
    float2 b = *(const float2*)&hi[ed_s[j + 1].y * 128 + d2];
    sx += a.x + b.x; sy += a.y + b.y;
  }
  if (j < e1) {
    float2 a = *(const float2*)&hi[ed_s[j].y * 128 + d2];
    sx += a.x; sy += a.y;
  }
  float2 hv = *(const float2*)&hi[m * 128 + d2];
  *(float2*)&ho[m * 128 + d2] = make_float2(hv.x + sx, hv.y + sy);
}

// ---- motif gather ----
__global__ __launch_bounds__(128) void motif_gather_kernel(
    const float* __restrict__ xm_nodes, const int* __restrict__ mb,
    const int* __restrict__ node_s, const int* __restrict__ motifid,
    const float* __restrict__ emb, float* __restrict__ xm_h, int M) {
  const int m = blockIdx.x * 2 + (threadIdx.x >> 6);
  if (m >= M) return;
  const int d2 = (threadIdx.x & 63) * 2;
  float2 e = *(const float2*)&emb[motifid[m] * 128 + d2];
  float sx = e.x, sy = e.y;
  const int j0 = mb[m], j1 = mb[m + 1];
  int j = j0;
  for (; j + 1 < j1; j += 2) {
    float2 a = *(const float2*)&xm_nodes[(long long)node_s[j] * 128 + d2];
    float2 b = *(const float2*)&xm_nodes[(long long)node_s[j + 1] * 128 + d2];
    sx += a.x + b.x; sy += a.y + b.y;
  }
  if (j < j1) {
    float2 a = *(const float2*)&xm_nodes[(long long)node_s[j] * 128 + d2];
    sx += a.x; sy += a.y;
  }
  *(float2*)&xm_h[m * 128 + d2] = make_float2(sx, sy);
}

// ---------------- weight preconversion ----------------
struct WSrc { const float* p[13]; };

__global__ __launch_bounds__(256) void convw_kernel(WSrc wsrc, ushort* __restrict__ Wf) {
  const int mat = blockIdx.x >> 2;
  const int kc  = blockIdx.x & 3;
  const float* W = wsrc.p[mat];
  const int t = threadIdx.x;
  #pragma unroll
  for (int i = 0; i < 16; ++i) {
    int o = t * 16 + i;
    int nt = o >> 9, lane = (o >> 3) & 63, j = o & 7;
    int k = kc * 32 + (lane >> 4) * 8 + j;
    int n = nt * 16 + (lane & 15);
    unsigned hi, lo;
    split_bf(W[k * 128 + n], hi, lo);
    Wf[mat * 32768 + kc * 4096 + o]         = (ushort)hi;
    Wf[mat * 32768 + 16384 + kc * 4096 + o] = (ushort)lo;
  }
}

// ---------------- MFMA GEMM core: 128x128 tile, 512 threads / 8 waves, 64x32 per wave ----------------
__device__ __forceinline__ void stage_a_bf(ushort* AsH, ushort* AsL,
                                           const float* __restrict__ src,
                                           int row0, int nrows, int tid) {
  #pragma unroll
  for (int it = 0; it < 8; ++it) {
    int idx = (it * 512 + tid) * 4;
    int r = idx >> 7, k = idx & 127;
    float4 v = make_float4(0.f, 0.f, 0.f, 0.f);
    if (row0 + r < nrows) v = *(const float4*)&src[(long long)(row0 + r) * 128 + k];
    unsigned h0, l0, h1, l1, h2, l2, h3, l3;
    split_bf(v.x, h0, l0); split_bf(v.y, h1, l1);
    split_bf(v.z, h2, l2); split_bf(v.w, h3, l3);
    uint2 ph = make_uint2(h0 | (h1 << 16), h2 | (h3 << 16));
    uint2 pl = make_uint2(l0 | (l1 << 16), l2 | (l3 << 16));
    int boff = r * 256 + ((k * 2) ^ ((r & 7) << 4));
    *(uint2*)((char*)AsH + boff) = ph;
    *(uint2*)((char*)AsL + boff) = pl;
  }
}

__device__ __forceinline__ bf16x8 ld_afrag(const ushort* As, int row, int k0) {
  int boff = row * 256 + ((k0 * 2) ^ ((row & 7) << 4));
  return *(const bf16x8*)((const char*)As + boff);
}

__device__ __forceinline__ bf16x8 ld_wfrag(const ushort* Wf, int kc, int nt, int lane) {
  return ((const bf16x8*)Wf)[(kc * 8 + nt) * 64 + lane];
}

// acc += A * W  (3-pass hi/lo). Wave covers rows wr*64..+64, cols wc*32..+32.
__device__ __forceinline__ void mfma_gemm(const ushort* AsH, const ushort* AsL,
                                          const ushort* WfH, const ushort* WfL,
                                          int wr, int wc, int lane, f32x4 (&acc)[4][2]) {
  #pragma unroll
  for (int kc = 0; kc < 4; ++kc) {
    const int k0 = kc * 32 + (lane >> 4) * 8;
    bf16x8 ah[4], al[4], wh[2], wl[2];
    #pragma unroll
    for (int rt = 0; rt < 4; ++rt) {
      int row = wr * 64 + rt * 16 + (lane & 15);
      ah[rt] = ld_afrag(AsH, row, k0);
      al[rt] = ld_afrag(AsL, row, k0);
    }
    #pragma unroll
    for (int ct = 0; ct < 2; ++ct) {
      int nt = wc * 2 + ct;
      wh[ct] = ld_wfrag(WfH, kc, nt, lane);
      wl[ct] = ld_wfrag(WfL, kc, nt, lane);
    }
    #pragma unroll
    for (int rt = 0; rt < 4; ++rt)
      #pragma unroll
      for (int ct = 0; ct < 2; ++ct) {
        acc[rt][ct] = __builtin_amdgcn_mfma_f32_16x16x32_bf16(ah[rt], wh[ct], acc[rt][ct], 0, 0, 0);
        acc[rt][ct] = __builtin_amdgcn_mfma_f32_16x16x32_bf16(ah[rt], wl[ct], acc[rt][ct], 0, 0, 0);
        acc[rt][ct] = __builtin_amdgcn_mfma_f32_16x16x32_bf16(al[rt], wh[ct], acc[rt][ct], 0, 0, 0);
      }
  }
}

__device__ __forceinline__ void bias_acc(f32x4 (&acc)[4][2], const float* __restrict__ b,
                                         int wc, int lane) {
  #pragma unroll
  for (int ct = 0; ct < 2; ++ct) {
    float bv = b[wc * 32 + ct * 16 + (lane & 15)];
    #pragma unroll
    for (int rt = 0; rt < 4; ++rt) acc[rt][ct] = (f32x4){bv, bv, bv, bv};
  }
}

// out = relu( relu(h@W1 + b1) @ W2 + b2 ), fused two GEMMs
__global__ __launch_bounds__(512, 2) void mlp_mfma_kernel(
    const float* __restrict__ h,
    const ushort* __restrict__ W1f, const float* __restrict__ b1,
    const ushort* __restrict__ W2f, const float* __restrict__ b2,
    float* __restrict__ out, int nrows) {
  __shared__ ushort AsH[128 * 128];
  __shared__ ushort AsL[128 * 128];
  const int tid = threadIdx.x;
  const int lane = tid & 63;
  const int w = tid >> 6;          // 0..7
  const int wr = w >> 2, wc = w & 3;
  const int row0 = blockIdx.x * 128;

  stage_a_bf(AsH, AsL, h, row0, nrows, tid);
  __syncthreads();

  f32x4 acc[4][2];
  bias_acc(acc, b1, wc, lane);
  mfma_gemm(AsH, AsL, W1f, W1f + 16384, wr, wc, lane, acc);
  __syncthreads();

  // H = relu(acc) -> As planes (bf16 hi/lo, swizzled)
  #pragma unroll
  for (int rt = 0; rt < 4; ++rt)
    #pragma unroll
    for (int ct = 0; ct < 2; ++ct) {
      int col = wc * 32 + ct * 16 + (lane & 15);
      #pragma unroll
      for (int r = 0; r < 4; ++r) {
        int row = wr * 64 + rt * 16 + (lane >> 4) * 4 + r;
        unsigned hi, lo;
        split_bf(fmaxf(acc[rt][ct][r], 0.f), hi, lo);
        int boff = row * 256 + ((col * 2) ^ ((row & 7) << 4));
        *(ushort*)((char*)AsH + boff) = (ushort)hi;
        *(ushort*)((char*)AsL + boff) = (ushort)lo;
      }
    }
  __syncthreads();

  f32x4 acc2[4][2];
  bias_acc(acc2, b2, wc, lane);
  mfma_gemm(AsH, AsL, W2f, W2f + 16384, wr, wc, lane, acc2);

  #pragma unroll
  for (int rt = 0; rt < 4; ++rt)
    #pragma unroll
    for (int ct = 0; ct < 2; ++ct) {
      int col = wc * 32 + ct * 16 + (lane & 15);
      #pragma unroll
      for (int r = 0; r < 4; ++r) {
        int row = row0 + wr * 64 + rt * 16 + (lane >> 4) * 4 + r;
        if (row < nrows) out[(long long)row * 128 + col] = fmaxf(acc2[rt][ct][r], 0.f);
      }
    }
}

// xm_nodes = relu([x1|x2|x3] @ lin_W + lin_b), K=384 via 3 staged chunks
__global__ __launch_bounds__(512, 2) void lin_mfma_kernel(
    const float* __restrict__ x1, const float* __restrict__ x2, const float* __restrict__ x3,
    const ushort* __restrict__ Wlf, const float* __restrict__ lb,
    float* __restrict__ xm_nodes, int nrows) {
  __shared__ ushort AsH[128 * 128];
  __shared__ ushort AsL[128 * 128];
  const int tid = threadIdx.x;
  const int lane = tid & 63;
  const int w = tid >> 6;
  const int wr = w >> 2, wc = w & 3;
  const int row0 = blockIdx.x * 128;

  f32x4 acc[4][2];
  bias_acc(acc, lb, wc, lane);

  for (int c3 = 0; c3 < 3; ++c3) {
    const float* xs = (c3 == 0) ? x1 : (c3 == 1 ? x2 : x3);
    if (c3) __syncthreads();
    stage_a_bf(AsH, AsL, xs, row0, nrows, tid);
    __syncthreads();
    const ushort* Wc = Wlf + c3 * 32768;
    mfma_gemm(AsH, AsL, Wc, Wc + 16384, wr, wc, lane, acc);
  }

  #pragma unroll
  for (int rt = 0; rt < 4; ++rt)
    #pragma unroll
    for (int ct = 0; ct < 2; ++ct) {
      int col = wc * 32 + ct * 16 + (lane & 15);
      #pragma unroll
      for (int r = 0; r < 4; ++r) {
        int row = row0 + wr * 64 + rt * 16 + (lane >> 4) * 4 + r;
        if (row < nrows) xm_nodes[(long long)row * 128 + col] = fmaxf(acc[rt][ct][r], 0.f);
      }
    }
}

// chunked node pooling over sorted batch[]
__global__ __launch_bounds__(192) void xg_pool_kernel(
    const float* __restrict__ x1, const float* __restrict__ x2, const float* __restrict__ x3,
    const int* __restrict__ batch, int N, int chunk, float* __restrict__ outg) {
  const int c0 = blockIdx.x * chunk;
  if (c0 >= N) return;
  const int c1 = min(c0 + chunk, N);
  const int l = threadIdx.x >> 6;
  const int d2 = (threadIdx.x & 63) * 2;
  const float* xs = (l == 0) ? x1 : (l == 1 ? x2 : x3);
  int b = batch[c0];
  float sx = 0.f, sy = 0.f;
  for (int n = c0; n < c1; ++n) {
    int bn = batch[n];
    if (bn != b) {
      if (sx != 0.f) atomicAdd(&outg[b * 384 + l * 128 + d2], sx);
      if (sy != 0.f) atomicAdd(&outg[b * 384 + l * 128 + d2 + 1], sy);
      sx = 0.f; sy = 0.f; b = bn;
    }
    float2 v = *(const float2*)&xs[n * 128 + d2];
    sx += v.x; sy += v.y;
  }
  atomicAdd(&outg[b * 384 + l * 128 + d2], sx);
  atomicAdd(&outg[b * 384 + l * 128 + d2 + 1], sy);
}

// chunked motif pooling
__global__ __launch_bounds__(128) void xm_pool_kernel(
    const float* __restrict__ m1, const float* __restrict__ m2,
    const int* __restrict__ partial, int B, int M, int chunk,
    float* __restrict__ outm) {
  const int c0 = blockIdx.x * chunk;
  if (c0 >= M) return;
  const int c1 = min(c0 + chunk, M);
  const int l = threadIdx.x >> 6;
  const int d2 = (threadIdx.x & 63) * 2;
  const float* ms = (l == 0) ? m1 : m2;
  int b = 0;
  while (b + 1 < B && partial[b + 1] <= c0) ++b;
  int bend = (b + 1 < B) ? partial[b + 1] : M;
  float sx = 0.f, sy = 0.f;
  for (int m = c0; m < c1; ++m) {
    if (m >= bend) {
      if (sx != 0.f) atomicAdd(&outm[b * 256 + l * 128 + d2], sx);
      if (sy != 0.f) atomicAdd(&outm[b * 256 + l * 128 + d2 + 1], sy);
      sx = 0.f; sy = 0.f;
      do { ++b; } while (b + 1 < B && partial[b + 1] <= m);
      bend = (b + 1 < B) ? partial[b + 1] : M;
    }
    float2 v = *(const float2*)&ms[m * 128 + d2];
    sx += v.x; sy += v.y;
  }
  atomicAdd(&outm[b * 256 + l * 128 + d2], sx);
  atomicAdd(&outm[b * 256 + l * 128 + d2 + 1], sy);
}

extern "C" void kernel_launch(void* const* d_in, const int* in_sizes, int n_in,
                              void* d_out, int out_size, void* d_ws, size_t ws_size,
                              hipStream_t stream) {
  const float* x       = (const float*)d_in[0];
  const float* ea      = (const float*)d_in[1];
  const int*   eidx    = (const int*)d_in[2];
  const int*   batch   = (const int*)d_in[3];
  const int*   n2m     = (const int*)d_in[4];
  const int*   nmot    = (const int*)d_in[5];
  const int*   meidx   = (const int*)d_in[6];
  const int*   motifid = (const int*)d_in[7];
  const float* gcW1 = (const float*)d_in[8];
  const float* gcb1 = (const float*)d_in[9];
  const float* gcW2 = (const float*)d_in[10];
  const float* gcb2 = (const float*)d_in[11];
  const float* mcW1 = (const float*)d_in[12];
  const float* mcb1 = (const float*)d_in[13];
  const float* mcW2 = (const float*)d_in[14];
  const float* mcb2 = (const float*)d_in[15];
  const float* linW = (const float*)d_in[16];
  const float* linb = (const float*)d_in[17];
  const float* emb  = (const float*)d_in[18];
  float* outp = (float*)d_out;

  const int N  = in_sizes[0] / 128;   // 50000
  const int E  = in_sizes[1] / 128;   // 600000
  const int B  = in_sizes[5];         // 64
  const int ME = in_sizes[6] / 2;     // 50000
  const int M  = in_sizes[7];         // 6400

  const size_t nodeBytes = (size_t)N * 128 * 4;
  const size_t motBytes  = (size_t)M * 128 * 4;
  char* ws = (char*)d_ws;
  float* xl0 = (float*)ws;                 ws += nodeBytes;
  float* xl1 = (float*)ws;                 ws += nodeBytes;
  float* xl2 = (float*)ws;                 ws += nodeBytes;
  char*  R   = ws;                         ws += nodeBytes;   // h during GINE; xm_nodes after
  __half* ea_s = (__half*)ws;              ws += (size_t)E * 128 * 2;   // 154 MB fp16 CSR-ordered ea
  ushort* Wf = (ushort*)ws;                ws += (size_t)13 * 32768 * 2;
  int* counts  = (int*)ws;                 ws += (size_t)N * 4;
  int* base    = (int*)ws;                 ws += (size_t)(N + 1) * 4;
  int* cursor  = (int*)ws;                 ws += (size_t)N * 4;
  int2* ed_s   = (int2*)ws;                ws += (size_t)E * 8;
  int* mcounts = (int*)ws;                 ws += (size_t)M * 4;
  int* mbase   = (int*)ws;                 ws += (size_t)(M + 1) * 4;
  int* mcursor = (int*)ws;                 ws += (size_t)M * 4;
  int2* med_s  = (int2*)ws;                ws += (size_t)ME * 8;
  int* nmcnt   = (int*)ws;                 ws += (size_t)M * 4;
  int* nmbase  = (int*)ws;                 ws += (size_t)(M + 1) * 4;
  int* nmcur   = (int*)ws;                 ws += (size_t)M * 4;
  int* node_s  = (int*)ws;                 ws += (size_t)N * 4;
  int* partial = (int*)ws;                 ws += 256;
  int* bnd     = (int*)ws;                 ws += 512;
  if ((size_t)(ws - (char*)d_ws) > ws_size) return;

  float* hbuf     = (float*)R;
  float* xm_nodes = (float*)R;
  float* xmh = (float*)((char*)xl0);
  float* hm  = (float*)((char*)xl0 + motBytes);
  float* ml0 = (float*)((char*)xl0 + 2 * motBytes);
  float* ml1 = (float*)((char*)xl0 + 3 * motBytes);

  hipMemsetAsync(outp, 0, (size_t)out_size * 4, stream);

  prep_kernel<<<1, 128, 0, stream>>>(nmot, batch, N, B, partial, bnd);

  // ---- preconvert weights ----
  WSrc wsrc;
  wsrc.p[0] = gcW1;            wsrc.p[1] = gcW1 + 16384;  wsrc.p[2] = gcW1 + 32768;
  wsrc.p[3] = gcW2;            wsrc.p[4] = gcW2 + 16384;  wsrc.p[5] = gcW2 + 32768;
  wsrc.p[6] = mcW1;            wsrc.p[7] = mcW1 + 16384;
  wsrc.p[8] = mcW2;            wsrc.p[9] = mcW2 + 16384;
  wsrc.p[10] = linW;           wsrc.p[11] = linW + 16384; wsrc.p[12] = linW + 32768;
  convw_kernel<<<52, 256, 0, stream>>>(wsrc, Wf);

  // ---- node-graph CSR by dst (packed eid,src) ----
  const int* src = eidx;
  const int* dst = eidx + E;
  hipMemsetAsync(counts, 0, (size_t)N * 4, stream);
  hist_kernel<<<(E + 255) / 256, 256, 0, stream>>>(dst, E, counts);
  scan_kernel<<<1, 1024, 0, stream>>>(counts, N, base, cursor);
  scatter_kernel<<<(E + 255) / 256, 256, 0, stream>>>(src, dst, E, cursor, ed_s);

  // ---- motif-graph CSR by dst ----
  const int* msrc = meidx;
  const int* mdst = meidx + ME;
  hipMemsetAsync(mcounts, 0, (size_t)M * 4, stream);
  hist_kernel<<<(ME + 255) / 256, 256, 0, stream>>>(mdst, ME, mcounts);
  scan_kernel<<<1, 1024, 0, stream>>>(mcounts, M, mbase, mcursor);
  scatter_kernel<<<(ME + 255) / 256, 256, 0, stream>>>(msrc, mdst, ME, mcursor, med_s);

  // ---- node->motif CSR ----
  hipMemsetAsync(nmcnt, 0, (size_t)M * 4, stream);
  nm_hist_kernel<<<(N + 255) / 256, 256, 0, stream>>>(n2m, batch, partial, N, nmcnt);
  scan_kernel<<<1, 1024, 0, stream>>>(nmcnt, M, nmbase, nmcur);
  nm_scatter_kernel<<<(N + 255) / 256, 256, 0, stream>>>(n2m, batch, partial, N, nmcur, node_s);

  // ---- GINE stack ----
  float* xo[3] = {xl0, xl1, xl2};
  const int ngrid = (N + 127) / 128;
  gine_first_kernel<<<(N + 1) / 2, 128, 0, stream>>>(x, ea, base, ed_s, ea_s, hbuf, N);
  mlp_mfma_kernel<<<ngrid, 512, 0, stream>>>(hbuf,
      Wf + (size_t)0 * 32768, gcb1, Wf + (size_t)3 * 32768, gcb2, xl0, N);
  for (int i = 1; i < 3; ++i) {
    gine_rest_kernel<<<(N + 1) / 2, 128, 0, stream>>>(xo[i - 1], ea_s, base, ed_s, hbuf, N);
    mlp_mfma_kernel<<<ngrid, 512, 0, stream>>>(hbuf,
        Wf + (size_t)(0 + i) * 32768, gcb1 + i * 128,
        Wf + (size_t)(3 + i) * 32768, gcb2 + i * 128, xo[i], N);
  }
  {
    const int nb = 512;
    const int chunk = (N + nb - 1) / nb;
    xg_pool_kernel<<<nb, 192, 0, stream>>>(xl0, xl1, xl2, batch, N, chunk, outp + B * 256);
  }

  // ---- motif features ----
  lin_mfma_kernel<<<ngrid, 512, 0, stream>>>(xl0, xl1, xl2, Wf + (size_t)10 * 32768, linb,
                                             xm_nodes, N);
  motif_gather_kernel<<<(M + 1) / 2, 128, 0, stream>>>(xm_nodes, nmbase, node_s,
                                                       motifid, emb, xmh, M);

  // ---- motif GIN stack ----
  const float* hs[2] = {xmh, ml0};
  float* mo[2] = {ml0, ml1};
  const int mgrid = (M + 127) / 128;
  for (int i = 0; i < 2; ++i) {
    gin_agg_kernel<<<(M + 1) / 2, 128, 0, stream>>>(hs[i], mbase, med_s, hm, M);
    mlp_mfma_kernel<<<mgrid, 512, 0, stream>>>(hm,
        Wf + (size_t)(6 + i) * 32768, mcb1 + i * 128,
        Wf + (size_t)(8 + i) * 32768, mcb2 + i * 128, mo[i], M);
  }
  {
    const int nb = 256;
    const int chunk = (M + nb - 1) / nb;
    xm_pool_kernel<<<nb, 128, 0, stream>>>(ml0, ml1, partial, B, M, chunk, outp);
  }
}